// Round 5
// baseline (1220.103 us; speedup 1.0000x reference)
//
#include <hip/hip_runtime.h>

#define BB 8
#define TT 2048
#define CC 1024
#define FF 4096
#define MM (BB*TT)   // 16384

typedef unsigned short u16;
typedef __bf16 bf16x8 __attribute__((ext_vector_type(8)));
typedef float f32x16 __attribute__((ext_vector_type(16)));

__device__ __forceinline__ u16 f2bf(float f) {
  unsigned int u = __float_as_uint(f);
  u += 0x7fffu + ((u >> 16) & 1u);     // RNE to bf16
  return (u16)(u >> 16);
}
__device__ __forceinline__ float bf2f(u16 h) {
  unsigned int u = ((unsigned int)h) << 16;
  return __uint_as_float(u);
}
__device__ __forceinline__ float sigm(float x) { return 1.f / (1.f + __expf(-x)); }

__device__ __forceinline__ void async16(const void* g, void* l) {
  __builtin_amdgcn_global_load_lds(
      (const __attribute__((address_space(1))) unsigned int*)g,
      (__attribute__((address_space(3))) unsigned int*)l, 16, 0, 0);
}

// ---------------------------------------------------------------------------
// NT GEMM: C[m,n] = sum_k A[m,k]*W[n,k], A [M,K] bf16 row-major, W [N,K] bf16.
// 128x128 tile, BK=64, 256 thr (4 waves, each 64x64 = 2x2 of 32x32x16 MFMA).
// LDS layout is chunk-major per 32-row group: addr(row,chunk) =
//   (grp(row)*256 + chunk*32 + (row&31)) * 16B, grp = row>>5, chunk = k>>3.
// -> every fragment ds_read_b128 is base + lane*16 (perfectly linear, zero
//    bank conflicts), and global_load_lds staging satisfies the wave-uniform
//    base + lane*16 constraint (global side: 16B/lane scattered, L2-absorbed).
// GROUP_M=16 tile swizzle keeps the A working set L2/L3-resident.
// MODE 0: Cf[idx] = v (f32).
// MODE 2: Cb[idx] = bf16(relu(v)^2).
// MODE 3: Cb[idx] = bf16(v).
// MODE 4: Cf[idx] += sigm(R[idx]) * v (f32 in-place; R bf16).
// ---------------------------------------------------------------------------
#define GROUP_M 16

template<int MODE>
__device__ __forceinline__ void gemm_body(
    const u16* __restrict__ A, const u16* __restrict__ W,
    float* __restrict__ Cf, u16* __restrict__ Cb,
    const u16* __restrict__ R, int N, int K)
{
  __shared__ __align__(16) u16 ldsA[128 * 64];
  __shared__ __align__(16) u16 ldsB[128 * 64];
  const int tid  = threadIdx.x;
  const int wave = tid >> 6;
  const int lane = tid & 63;

  // tile swizzle (grid.x = M-tiles, divisible by GROUP_M; grid.y = N-tiles)
  const int bid  = blockIdx.x + blockIdx.y * gridDim.x;
  const int gsz  = GROUP_M * gridDim.y;
  const int gid  = bid / gsz;
  const int rem  = bid - gid * gsz;
  const int bm   = (gid * GROUP_M + (rem % GROUP_M)) * 128;
  const int bn   = (rem / GROUP_M) * 128;

  const int wm = (wave >> 1) * 64;   // 0 or 64
  const int wn = (wave & 1) * 64;
  const int l31 = lane & 31;
  const int l5  = lane >> 5;         // 0/1

  // staging: round g covers row-group g (32 rows); wave w covers k-chunks
  // {2w, 2w+1}; lane l -> (chunk = 2w + (l>>5), row = l&31).
  const int cA = 2 * wave + l5;
  const u16* gAp[4]; const u16* gBp[4];
  u16* lAp[4]; u16* lBp[4];
#pragma unroll
  for (int g = 0; g < 4; ++g) {
    gAp[g] = A + (size_t)(bm + g * 32 + l31) * K + cA * 8;
    gBp[g] = W + (size_t)(bn + g * 32 + l31) * K + cA * 8;
    lAp[g] = &ldsA[g * 2048 + wave * 512 + lane * 8];
    lBp[g] = &ldsB[g * 2048 + wave * 512 + lane * 8];
  }

  // fragment reads: a(mi,t) at group (wm>>5)+mi, chunk 2t+l5, row l31
  //   offset = ((wm>>5)+mi)*2048 + t*512 + lane*8  (linear in lane)
  const int aoff = (wm >> 5) * 2048 + lane * 8;
  const int boff = (wn >> 5) * 2048 + lane * 8;

  f32x16 acc[2][2] = {};

  for (int kt = 0; kt < K; kt += 64) {
#pragma unroll
    for (int g = 0; g < 4; ++g) async16(gAp[g] + kt, lAp[g]);
#pragma unroll
    for (int g = 0; g < 4; ++g) async16(gBp[g] + kt, lBp[g]);
    __syncthreads();
#pragma unroll
    for (int t = 0; t < 4; ++t) {
      bf16x8 a0 = *(const bf16x8*)&ldsA[aoff + t * 512];
      bf16x8 a1 = *(const bf16x8*)&ldsA[aoff + 2048 + t * 512];
      bf16x8 b0 = *(const bf16x8*)&ldsB[boff + t * 512];
      bf16x8 b1 = *(const bf16x8*)&ldsB[boff + 2048 + t * 512];
      acc[0][0] = __builtin_amdgcn_mfma_f32_32x32x16_bf16(a0, b0, acc[0][0], 0, 0, 0);
      acc[0][1] = __builtin_amdgcn_mfma_f32_32x32x16_bf16(a0, b1, acc[0][1], 0, 0, 0);
      acc[1][0] = __builtin_amdgcn_mfma_f32_32x32x16_bf16(a1, b0, acc[1][0], 0, 0, 0);
      acc[1][1] = __builtin_amdgcn_mfma_f32_32x32x16_bf16(a1, b1, acc[1][1], 0, 0, 0);
    }
    __syncthreads();
  }

  // 32x32 C/D layout (verified m74/m101): col = lane&31,
  // row = (reg&3) + 8*(reg>>2) + 4*(lane>>5)
  const int row00 = bm + wm + 4 * l5;
  const int col00 = bn + wn + l31;
#pragma unroll
  for (int mi = 0; mi < 2; ++mi)
#pragma unroll
    for (int ni = 0; ni < 2; ++ni) {
#pragma unroll
      for (int r = 0; r < 16; ++r) {
        const int row = row00 + mi * 32 + (r & 3) + 8 * (r >> 2);
        const size_t idx = (size_t)row * N + (col00 + ni * 32);
        const float v = acc[mi][ni][r];
        if (MODE == 0) Cf[idx] = v;
        if (MODE == 2) { float rl = v > 0.f ? v : 0.f; Cb[idx] = f2bf(rl * rl); }
        if (MODE == 3) Cb[idx] = f2bf(v);
        if (MODE == 4) Cf[idx] += sigm(bf2f(R[idx])) * v;
      }
    }
}

template<int MODE>
__global__ __launch_bounds__(256, 2) void gemm_bt(
    const u16* __restrict__ A, const u16* __restrict__ W,
    float* __restrict__ Cf, u16* __restrict__ Cb,
    const u16* __restrict__ R, int N, int K)
{
  gemm_body<MODE>(A, W, Cf, Cb, R, N, K);
}

// ---------------------------------------------------------------------------
// LayerNorm both rows t and t-1, time-shift mix, bf16 cast.
// One block per row (b,t). ov/oxb may be null (phase-2 use).
// oxb (raw x cast) is written at pitch 2*CC (the A' interleaved buffer).
// ---------------------------------------------------------------------------
__global__ __launch_bounds__(256) void prep_mix(
    const float* __restrict__ x,
    const float* __restrict__ lnw, const float* __restrict__ lnb,
    const float* __restrict__ mk, const float* __restrict__ mv, const float* __restrict__ mr,
    u16* __restrict__ ok, u16* __restrict__ ov, u16* __restrict__ orr,
    u16* __restrict__ oxb)
{
  const int m = blockIdx.x;
  const int t = m & (TT - 1);
  const int tid = threadIdx.x;
  const int wave = tid >> 6, lane = tid & 63;
  const bool hasp = (t != 0);

  const float4 xc4 = ((const float4*)(x + (size_t)m * CC))[tid];
  float4 xp4 = make_float4(0.f, 0.f, 0.f, 0.f);
  if (hasp) xp4 = ((const float4*)(x + (size_t)(m - 1) * CC))[tid];

  float s0 = xc4.x + xc4.y + xc4.z + xc4.w;
  float s1 = xc4.x*xc4.x + xc4.y*xc4.y + xc4.z*xc4.z + xc4.w*xc4.w;
  float s2 = xp4.x + xp4.y + xp4.z + xp4.w;
  float s3 = xp4.x*xp4.x + xp4.y*xp4.y + xp4.z*xp4.z + xp4.w*xp4.w;
#pragma unroll
  for (int off2 = 32; off2 > 0; off2 >>= 1) {
    s0 += __shfl_xor(s0, off2);
    s1 += __shfl_xor(s1, off2);
    s2 += __shfl_xor(s2, off2);
    s3 += __shfl_xor(s3, off2);
  }
  __shared__ float red[4][4];
  if (lane == 0) { red[0][wave] = s0; red[1][wave] = s1; red[2][wave] = s2; red[3][wave] = s3; }
  __syncthreads();
  const float S0 = red[0][0] + red[0][1] + red[0][2] + red[0][3];
  const float S1 = red[1][0] + red[1][1] + red[1][2] + red[1][3];
  const float S2 = red[2][0] + red[2][1] + red[2][2] + red[2][3];
  const float S3 = red[3][0] + red[3][1] + red[3][2] + red[3][3];
  const float inv = 1.f / (float)CC;
  const float muc = S0 * inv, varc = S1 * inv - muc * muc, rsc = rsqrtf(varc + 1e-5f);
  const float mup = S2 * inv, varp = S3 * inv - mup * mup, rsp = rsqrtf(varp + 1e-5f);

  const float xc[4] = {xc4.x, xc4.y, xc4.z, xc4.w};
  const float xp[4] = {xp4.x, xp4.y, xp4.z, xp4.w};
  const float4 lw4 = ((const float4*)lnw)[tid];
  const float4 lb4 = ((const float4*)lnb)[tid];
  const float lw[4] = {lw4.x, lw4.y, lw4.z, lw4.w};
  const float lb[4] = {lb4.x, lb4.y, lb4.z, lb4.w};
  const float4 mk4 = ((const float4*)mk)[tid];
  const float mka[4] = {mk4.x, mk4.y, mk4.z, mk4.w};
  const float4 mr4 = ((const float4*)mr)[tid];
  const float mra[4] = {mr4.x, mr4.y, mr4.z, mr4.w};
  float mva[4] = {0.f, 0.f, 0.f, 0.f};
  if (ov) {
    const float4 mv4 = ((const float4*)mv)[tid];
    mva[0] = mv4.x; mva[1] = mv4.y; mva[2] = mv4.z; mva[3] = mv4.w;
  }

  ushort4 wk2, wv2, wr2, wb2;
  u16* pk = (u16*)&wk2; u16* pv = (u16*)&wv2; u16* pr = (u16*)&wr2; u16* pb = (u16*)&wb2;
#pragma unroll
  for (int j = 0; j < 4; ++j) {
    float h  = (xc[j] - muc) * rsc * lw[j] + lb[j];
    float hh = hasp ? (xp[j] - mup) * rsp * lw[j] + lb[j] : 0.f;
    pk[j] = f2bf(h * mka[j] + hh * (1.f - mka[j]));
    pv[j] = f2bf(h * mva[j] + hh * (1.f - mva[j]));
    pr[j] = f2bf(h * mra[j] + hh * (1.f - mra[j]));
    pb[j] = f2bf(xc[j]);
  }
  ((ushort4*)(ok + (size_t)m * CC))[tid] = wk2;
  if (ov)  ((ushort4*)(ov  + (size_t)m * CC))[tid] = wv2;
  ((ushort4*)(orr + (size_t)m * CC))[tid] = wr2;
  if (oxb) ((ushort4*)(oxb + (size_t)m * (2 * CC)))[tid] = wb2;   // A' xb half
}

// ---------------------------------------------------------------------------
// WKV blocked 3-phase parallel scan. Output goes to the rwkv half of the
// interleaved A' buffer: out pitch = 2*CC.
// ---------------------------------------------------------------------------
#define WKV_CPB 32
#define WKV_NCH 32
#define WKV_L   (TT / WKV_NCH)   // 64

__global__ __launch_bounds__(1024) void wkv_scan(
    const u16* __restrict__ k, const u16* __restrict__ v, const u16* __restrict__ r,
    const float* __restrict__ decay, const float* __restrict__ first,
    u16* __restrict__ out)   // points at A' + CC (rwkv half), pitch 2*CC
{
  const int b  = blockIdx.x >> 5;
  const int c0 = (blockIdx.x & 31) * WKV_CPB;
  const int tid = threadIdx.x;
  const int cl = tid & 31;
  const int j  = tid >> 5;
  const int c  = c0 + cl;

  const float w   = -__expf(decay[c]);
  const float lam = __expf(w);
  const float eu  = __expf(first[c]);

  const size_t base  = (size_t)b * TT * CC + (size_t)j * WKV_L * CC + c;
  size_t obase = ((size_t)b * TT + (size_t)j * WKV_L) * (2 * CC) + c;

  // phase 1: local scan (state only)
  float a = 0.f, bb = 0.f;
  size_t idx = base;
  for (int i = 0; i < WKV_L; ++i, idx += CC) {
    const float kt = bf2f(k[idx]), vt = bf2f(v[idx]);
    const float ek = __expf(kt);
    a  = fmaf(lam, a, ek * vt);
    bb = fmaf(lam, bb, ek);
  }

  // phase 2: exclusive carry scan over chunks
  __shared__ float sA[WKV_NCH][WKV_CPB];
  __shared__ float sB[WKV_NCH][WKV_CPB];
  sA[j][cl] = a; sB[j][cl] = bb;
  __syncthreads();
  if (tid < WKV_CPB) {
    float ca = 0.f, cb = 0.f;
    const float cw   = -__expf(decay[c0 + tid]);
    const float cLam = __expf(cw * (float)WKV_L);
#pragma unroll
    for (int q = 0; q < WKV_NCH; ++q) {
      const float ta = sA[q][tid], tb = sB[q][tid];
      sA[q][tid] = ca; sB[q][tid] = cb;
      ca = fmaf(cLam, ca, ta);
      cb = fmaf(cLam, cb, tb);
    }
  }
  __syncthreads();
  a = sA[j][cl]; bb = sB[j][cl];

  // phase 3: replay with carry-in, emit sigmoid(r)*y into A' rwkv half
  idx = base;
  for (int i = 0; i < WKV_L; ++i, idx += CC, obase += 2 * CC) {
    const float kt = bf2f(k[idx]), vt = bf2f(v[idx]), rt = bf2f(r[idx]);
    const float ek = __expf(kt);
    const float e2 = eu * ek;
    const float y  = (a + e2 * vt) / (bb + e2);
    out[obase] = f2bf(sigm(rt) * y);
    a  = fmaf(lam, a, ek * vt);
    bb = fmaf(lam, bb, ek);
  }
}

// ---------------------------------------------------------------------------
// Weight f32 -> bf16 conversion. Segments 3 (Wo) and 4 (Wsh) are interleaved
// into W' = [Wsh | Wo] rows of pitch 2048 for the merged short+Wo GEMM.
// ---------------------------------------------------------------------------
struct ConvArgs { const float* src[8]; int end[8]; int dstoff[8]; };

__global__ __launch_bounds__(256) void conv_w(ConvArgs args, u16* __restrict__ dst)
{
  const int i = (blockIdx.x * 256 + threadIdx.x) * 4;
  int seg = 0;
  const float* sp = args.src[0];
  int base = 0;
#pragma unroll
  for (int s = 1; s < 8; ++s) {
    if (i >= args.end[s - 1]) { seg = s; sp = args.src[s]; base = args.end[s - 1]; }
  }
  const int l = i - base;
  const float4 vv = *(const float4*)(sp + l);
  int dsti;
  if (seg == 3)      { int row = l >> 10, col = l & 1023; dsti = args.dstoff[3] + row * 2048 + 1024 + col; }
  else if (seg == 4) { int row = l >> 10, col = l & 1023; dsti = args.dstoff[4] + row * 2048 + col; }
  else               dsti = args.dstoff[seg] + l;
  ushort4 d;
  d.x = f2bf(vv.x); d.y = f2bf(vv.y); d.z = f2bf(vv.z); d.w = f2bf(vv.w);
  *(ushort4*)(dst + dsti) = d;
}

extern "C" void kernel_launch(void* const* d_in, const int* in_sizes, int n_in,
                              void* d_out, int out_size, void* d_ws, size_t ws_size,
                              hipStream_t stream)
{
  const float* x    = (const float*)d_in[0];
  const float* ln1w = (const float*)d_in[1];
  const float* ln1b = (const float*)d_in[2];
  const float* ln2w = (const float*)d_in[3];
  const float* ln2b = (const float*)d_in[4];
  const float* tdec = (const float*)d_in[5];
  const float* tfir = (const float*)d_in[6];
  const float* amk  = (const float*)d_in[7];
  const float* amv  = (const float*)d_in[8];
  const float* amr  = (const float*)d_in[9];
  const float* Wk   = (const float*)d_in[10];
  const float* Wv   = (const float*)d_in[11];
  const float* Wr   = (const float*)d_in[12];
  const float* Wo   = (const float*)d_in[13];
  const float* fmk  = (const float*)d_in[14];
  const float* fmr  = (const float*)d_in[15];
  const float* WfK  = (const float*)d_in[16];
  const float* WfR  = (const float*)d_in[17];
  const float* WfV  = (const float*)d_in[18];
  const float* Wsh  = (const float*)d_in[19];
  float* out = (float*)d_out;
  char* ws = (char*)d_ws;

  // workspace: 28 MB bf16 weights + six 32 MB regions = 230,686,720 B total.
  u16* wW = (u16*)(ws);
  u16* U0 = (u16*)(ws + 29360128);
  u16* U1 = (u16*)(ws + 62914560);
  u16* U2 = (u16*)(ws + 96468992);
  u16* U3 = (u16*)(ws + 130023424);
  u16* U4 = (u16*)(ws + 163577856);   // A' = U4+U5, 64 MB contiguous

  // liveness-based aliases:
  u16* xk   = U0;          // prep1
  u16* xv   = U1;
  u16* xr   = U2;
  u16* Ap   = U4;          // A' [M, 2C]: cols 0..C-1 = bf16(x), C..2C-1 = rwkv
  u16* kbuf = U3;          // k = xk*Wk   (U0 dead after)
  u16* vbuf = U0;          // v = xv*Wv   (U1 dead after)
  u16* rbuf = U1;          // r = xr*Wr   (U2 dead after)
  u16* gk   = U0;          // prep2       (U0 dead after wkv)
  u16* gr   = U1;
  u16* kkb  = U2;          // kk [M,F] bf16 = 128 MB, spans U2..U5 (all dead)
  u16* rffn = U0;          // r_ffn       (gk/U0 dead after kk GEMM)

  u16* bWk   = wW + 0;
  u16* bWv   = wW + 1048576;
  u16* bWr   = wW + 2097152;
  u16* bWsWo = wW + 3145728;   // W' [C, 2C] interleaved [Wsh | Wo]
  u16* bWfR  = wW + 5242880;
  u16* bWfK  = wW + 6291456;
  u16* bWfV  = wW + 10485760;

  ConvArgs ca;
  ca.src[0] = Wk;  ca.src[1] = Wv;  ca.src[2] = Wr;  ca.src[3] = Wo;
  ca.src[4] = Wsh; ca.src[5] = WfR; ca.src[6] = WfK; ca.src[7] = WfV;
  const int e = 1048576;
  ca.end[0] = e;     ca.end[1] = 2*e;  ca.end[2] = 3*e;  ca.end[3] = 4*e;
  ca.end[4] = 5*e;   ca.end[5] = 6*e;  ca.end[6] = 10*e; ca.end[7] = 14*e;
  ca.dstoff[0] = 0;     ca.dstoff[1] = e;    ca.dstoff[2] = 2*e;
  ca.dstoff[3] = 3*e;   ca.dstoff[4] = 3*e;  // both into W' (interleaved)
  ca.dstoff[5] = 5*e;   ca.dstoff[6] = 6*e;  ca.dstoff[7] = 10*e;

  conv_w<<<14336, 256, 0, stream>>>(ca, wW);
  prep_mix<<<MM, 256, 0, stream>>>(x, ln1w, ln1b, amk, amv, amr, xk, xv, xr, Ap);

  dim3 g8(MM / 128, CC / 128);
  gemm_bt<3><<<g8, 256, 0, stream>>>(xk, bWk, nullptr, kbuf, nullptr, CC, CC);
  gemm_bt<3><<<g8, 256, 0, stream>>>(xv, bWv, nullptr, vbuf, nullptr, CC, CC);
  gemm_bt<3><<<g8, 256, 0, stream>>>(xr, bWr, nullptr, rbuf, nullptr, CC, CC);

  wkv_scan<<<BB * (CC / WKV_CPB), 1024, 0, stream>>>(kbuf, vbuf, rbuf, tdec, tfir, Ap + CC);

  // out = [xb | rwkv] * [Wsh | Wo]^T   (single K=2048 GEMM)
  gemm_bt<0><<<g8, 256, 0, stream>>>(Ap, bWsWo, out, nullptr, nullptr, CC, 2 * CC);

  prep_mix<<<MM, 256, 0, stream>>>(out, ln2w, ln2b, fmk, nullptr, fmr, gk, nullptr, gr, nullptr);

  dim3 gF(MM / 128, FF / 128);
  gemm_bt<2><<<gF, 256, 0, stream>>>(gk, bWfK, nullptr, kkb, nullptr, FF, CC);  // kk = relu(gk*WfK)^2
  gemm_bt<3><<<g8, 256, 0, stream>>>(gr, bWfR, nullptr, rffn, nullptr, CC, CC);
  // out += sigm(rffn) * (kk * WfV)   (fused final_add)
  gemm_bt<4><<<g8, 256, 0, stream>>>(kkb, bWfV, out, nullptr, rffn, CC, FF);
}